// Round 4
// baseline (513.806 us; speedup 1.0000x reference)
//
#include <hip/hip_runtime.h>
#include <cstdint>
#include <cstddef>

// Sizes fixed by the problem.
#define BTOK 1024
#define DDIM 1024
#define EEXP 16
#define HDIM 2048
#define ODIM 1024

typedef __bf16 bh;
typedef bh bh8 __attribute__((ext_vector_type(8)));
typedef bh bh4 __attribute__((ext_vector_type(4)));
typedef float fx4 __attribute__((ext_vector_type(4)));

__device__ __forceinline__ void gload16(const void* g, void* l) {
  // async global->LDS, 16B per lane; LDS dest is wave-uniform base + lane*16
  __builtin_amdgcn_global_load_lds(
      (const __attribute__((address_space(1))) void*)g,
      (__attribute__((address_space(3))) void*)l, 16, 0, 0);
}

// ---------------- transpose+convert+tile: fp32 [e][K][N] -> gload-ready tiles ----------------
// Output tile (e, nt, kt) is 4096 bh = 8 KB, contiguous, laid out so that
// gload16 with dst = task*16 reproduces the exact LDS image the GEMMs' COMPUTE
// expects: byte task*16 holds W[e][k0 + ((task&3)^(row&3))*8 + u][n0 + row],
// row = task>>2, u = 0..7.  (Same image round-1's strided staging produced.)
__global__ __launch_bounds__(256) void k_tcvt2(const float* __restrict__ in,
                                               bh* __restrict__ out, int K, int N,
                                               int KT, int NT) {
  const int kt = blockIdx.x, nt = blockIdx.y, e = blockIdx.z;
  const int k0 = kt * 32, n0 = nt * 128;
  const float* pin = in + (size_t)e * K * N + (size_t)k0 * N + n0;
  bh* pout = out + (((size_t)e * NT + nt) * KT + kt) * 4096;
  __shared__ float t[32][129];
  const int tid = threadIdx.x;
#pragma unroll
  for (int rep = 0; rep < 4; ++rep) {
    int idx = rep * 256 + tid;
    int kk = idx >> 5, c4 = (idx & 31) << 2;
    fx4 v = *(const fx4*)(pin + (size_t)kk * N + c4);
#pragma unroll
    for (int u = 0; u < 4; ++u) t[kk][c4 + u] = v[u];
  }
  __syncthreads();
#pragma unroll
  for (int rep = 0; rep < 2; ++rep) {
    int task = rep * 256 + tid;
    int row = task >> 2, s = task & 3, o = s ^ (row & 3);
    bh8 w;
#pragma unroll
    for (int u = 0; u < 8; ++u) w[u] = (bh)t[o * 8 + u][row];
    *(bh8*)(pout + (size_t)task * 8) = w;
  }
}

// ---------------- gating: one block per token ----------------
__global__ __launch_bounds__(256) void k_gating(
    const float* __restrict__ x, const float* __restrict__ wg,
    const float* __restrict__ wn, const float* __restrict__ nz,
    bh* __restrict__ xbf, unsigned* __restrict__ cnt,
    int* __restrict__ tok_buck, float* __restrict__ gate_buck,
    float* __restrict__ imp_part, float* __restrict__ load_part) {
  const int b = blockIdx.x, tid = threadIdx.x;
  __shared__ __align__(16) float xs[1024];
  __shared__ float part[32][9];
  __shared__ float vals[32];
  fx4 v = *(const fx4*)(x + (size_t)b * 1024 + tid * 4);
  *(fx4*)(xs + tid * 4) = v;
  bh4 xb;
#pragma unroll
  for (int u = 0; u < 4; ++u) xb[u] = (bh)v[u];
  *(bh4*)(xbf + (size_t)b * 1024 + tid * 4) = xb;
  __syncthreads();
  const int col = tid & 31, g = tid >> 5;
  const float* wp = ((col < 16) ? wg : wn) + (col & 15);
  float s = 0.f;
  for (int it = g * 128; it < g * 128 + 128; ++it) s += xs[it] * wp[it * 16];
  part[col][g] = s;
  __syncthreads();
  if (tid < 32) {
    float tsum = 0.f;
#pragma unroll
    for (int gg = 0; gg < 8; ++gg) tsum += part[tid][gg];
    vals[tid] = tsum;
  }
  __syncthreads();
  if (tid == 0) {
    float clean[16], sd[16], noisy[16];
#pragma unroll
    for (int e = 0; e < 16; ++e) {
      clean[e] = vals[e];
      float raw = vals[16 + e];
      float sp = fmaxf(raw, 0.f) + log1pf(expf(-fabsf(raw)));
      sd[e] = sp + 0.1f;
      noisy[e] = clean[e] + nz[b * 16 + e] * sd[e];
    }
    float tv[5]; int ti[5]; unsigned used = 0;
    for (int r = 0; r < 5; ++r) {
      float bst = -INFINITY; int bi = 0;
      for (int e = 0; e < 16; ++e)
        if (!((used >> e) & 1u) && noisy[e] > bst) { bst = noisy[e]; bi = e; }
      used |= 1u << bi; tv[r] = bst; ti[r] = bi;
    }
    float gts[4]; float se = 0.f;
#pragma unroll
    for (int k = 0; k < 4; ++k) { gts[k] = expf(tv[k] - tv[0]); se += gts[k]; }
#pragma unroll
    for (int k = 0; k < 4; ++k) gts[k] /= se;
    const float thr_in = tv[4], thr_out = tv[3];
    float imp[16];
#pragma unroll
    for (int e = 0; e < 16; ++e) imp[e] = 0.f;
    for (int k = 0; k < 4; ++k) imp[ti[k]] = gts[k];
    for (int e = 0; e < 16; ++e) imp_part[b * 16 + e] = imp[e];
    for (int e = 0; e < 16; ++e) {
      bool is_in = noisy[e] > thr_in;
      float z = (clean[e] - (is_in ? thr_in : thr_out)) / sd[e];
      load_part[b * 16 + e] = 0.5f * (1.f + erff(z * 0.70710678118654752f));
    }
    for (int k = 0; k < 4; ++k) {
      int ee = ti[k];
      unsigned p = atomicAdd(&cnt[ee], 1u);
      tok_buck[ee * 1024 + (int)p] = b;
      gate_buck[ee * 1024 + (int)p] = gts[k];
    }
  }
}

__device__ __forceinline__ float cv2_16(const float* v) {
  float m = 0.f;
  for (int i = 0; i < 16; ++i) m += v[i];
  m *= (1.f / 16.f);
  float var = 0.f;
  for (int i = 0; i < 16; ++i) { float d = v[i] - m; var += d * d; }
  var *= (1.f / 15.f);
  return var / (m * m + 1e-10f);
}

// ---------------- offsets + loss ----------------
__global__ __launch_bounds__(256) void k_finalize(
    const unsigned* __restrict__ cnt, unsigned* __restrict__ offs,
    const float* __restrict__ imp_part, const float* __restrict__ load_part,
    float* __restrict__ loss_out) {
  const int tid = threadIdx.x;
  __shared__ float red[256];
  __shared__ float impv[16], loadv[16];
  const int e = tid & 15, p = tid >> 4;
  float s = 0.f;
  for (int r = 0; r < 64; ++r) s += imp_part[((p * 64 + r) << 4) + e];
  red[tid] = s;
  __syncthreads();
  if (tid < 16) {
    float t = 0.f;
    for (int pp = 0; pp < 16; ++pp) t += red[pp * 16 + tid];
    impv[tid] = t;
  }
  __syncthreads();
  s = 0.f;
  for (int r = 0; r < 64; ++r) s += load_part[((p * 64 + r) << 4) + e];
  red[tid] = s;
  __syncthreads();
  if (tid < 16) {
    float t = 0.f;
    for (int pp = 0; pp < 16; ++pp) t += red[pp * 16 + tid];
    loadv[tid] = t;
  }
  __syncthreads();
  if (tid == 0) {
    unsigned o = 0;
    for (int ee = 0; ee < 16; ++ee) { offs[ee] = o; o += cnt[ee]; }
    loss_out[0] = (cv2_16(impv) + cv2_16(loadv)) * 1e-4f;
  }
}

// ---------------- GEMM1: h = relu(x @ W1[e] + b1[e]) for routed rows ----------------
// A = gathered bf16 x rows (gload_lds, pre-swizzled source), B = tiled w1t
// (contiguous 8 KB per K-step).  Depth-3 prefetch ring, counted vmcnt.
// 1D grid, XCD-aware decode: group (e,nt) shares its B panel; its 8 mt
// members sit at lid stride 8 -> same XCD, adjacent dispatch slots.
__global__ __launch_bounds__(256) void k_gemm1(
    const bh* __restrict__ xbf, const bh* __restrict__ w1t,
    const float* __restrict__ b1, const int* __restrict__ tok_buck,
    const unsigned* __restrict__ cnt, const unsigned* __restrict__ offs,
    bh* __restrict__ hbf) {
  const int lid = blockIdx.x;
  const int xcd = lid & 7, idx = lid >> 3;
  const int mt = idx & 7, g = xcd * 32 + (idx >> 3);
  const int e = g >> 4, nt = g & 15;
  const int ne = (int)cnt[e];
  if (mt * 128 >= ne) return;
  __shared__ __align__(16) bh As[4][128 * 32];
  __shared__ __align__(16) bh Bs[4][128 * 32];
  const int tid = threadIdx.x;
  const int lane = tid & 63, wv = tid >> 6, wm = wv >> 1, wn_ = wv & 1;

  const bh* a_src[2]; const bh* b_src[2];
  int dst_off[2];
#pragma unroll
  for (int r = 0; r < 2; ++r) {
    int task = r * 256 + tid;
    int row = task >> 2, s = task & 3;
    int gm = mt * 128 + row; if (gm >= ne) gm = ne - 1;
    int tok = tok_buck[e * 1024 + gm];
    a_src[r] = xbf + (size_t)tok * 1024 + ((s ^ (row & 3)) << 3);
    b_src[r] = w1t + (((size_t)e * 16 + nt) * 32) * 4096 + (size_t)task * 8;
    dst_off[r] = (r * 256 + (wv << 6)) << 4;  // byte offset within one buffer
  }
  const int ln15 = lane & 15, q = lane >> 4;
  const int qs = ((q ^ (ln15 & 3)) << 3);
  int a_off[4], b_off[4];
#pragma unroll
  for (int i = 0; i < 4; ++i) {
    a_off[i] = (wm * 64 + i * 16 + ln15) * 32 + qs;
    b_off[i] = (wn_ * 64 + i * 16 + ln15) * 32 + qs;
  }
  fx4 zero = {0.f, 0.f, 0.f, 0.f};
  fx4 acc[4][4];
#pragma unroll
  for (int i = 0; i < 4; ++i)
#pragma unroll
    for (int j = 0; j < 4; ++j) acc[i][j] = zero;

  auto stage = [&](int qb, int kt) {
    const int ko = kt * 32;             // A: elems within the row
    const size_t bo = (size_t)kt * 4096;  // B: contiguous 8 KB tiles
#pragma unroll
    for (int r = 0; r < 2; ++r) {
      gload16(a_src[r] + ko, (char*)(&As[qb][0]) + dst_off[r]);
      gload16(b_src[r] + bo, (char*)(&Bs[qb][0]) + dst_off[r]);
    }
  };

  const int NT = 32;
  stage(0, 0); stage(1, 1); stage(2, 2);
  asm volatile("s_waitcnt vmcnt(8)" ::: "memory");  // tile 0 landed (own wave)
  __builtin_amdgcn_s_barrier();                     // all waves' tile 0 landed

  for (int t = 0; t < NT; ++t) {
    if (t + 3 < NT) stage((t + 3) & 3, t + 3);
    const bh* Ab = &As[t & 3][0];
    const bh* Bb = &Bs[t & 3][0];
    bh8 af[4], bfr[4];
#pragma unroll
    for (int i = 0; i < 4; ++i) af[i] = *(const bh8*)(Ab + a_off[i]);
#pragma unroll
    for (int i = 0; i < 4; ++i) bfr[i] = *(const bh8*)(Bb + b_off[i]);
#pragma unroll
    for (int i = 0; i < 4; ++i)
#pragma unroll
      for (int j = 0; j < 4; ++j)
        acc[i][j] = __builtin_amdgcn_mfma_f32_16x16x32_bf16(af[i], bfr[j], acc[i][j], 0, 0, 0);
    // tile t+1 must be resident before anyone reads it next iter; keep t+2/t+3 in flight.
    if (t + 3 < NT)      asm volatile("s_waitcnt vmcnt(8) lgkmcnt(0)" ::: "memory");
    else if (t + 2 < NT) asm volatile("s_waitcnt vmcnt(4) lgkmcnt(0)" ::: "memory");
    else if (t + 1 < NT) asm volatile("s_waitcnt vmcnt(0) lgkmcnt(0)" ::: "memory");
    if (t + 1 < NT) __builtin_amdgcn_s_barrier();
  }

  int nrows = ne - mt * 128; if (nrows > 128) nrows = 128;
  int jn[4]; float b1v[4];
#pragma unroll
  for (int j = 0; j < 4; ++j) {
    jn[j] = nt * 128 + wn_ * 64 + j * 16 + ln15;
    b1v[j] = b1[e * 2048 + jn[j]];
  }
  const int rowbase = (int)offs[e] + mt * 128;
#pragma unroll
  for (int i = 0; i < 4; ++i)
#pragma unroll
    for (int rr = 0; rr < 4; ++rr) {
      int ml = wm * 64 + i * 16 + q * 4 + rr;
      if (ml < nrows) {
        size_t ro = (size_t)(rowbase + ml) * 2048;
#pragma unroll
        for (int j = 0; j < 4; ++j) {
          float vv = acc[i][j][rr] + b1v[j];
          hbf[ro + jn[j]] = (bh)fmaxf(vv, 0.f);
        }
      }
    }
}

// ---------------- GEMM2: y += gate * exp(h @ W2[e] + b2[e]) ----------------
// Group (e,mt) shares its A tile across the 8 nt members -> same XCD.
__global__ __launch_bounds__(256) void k_gemm2(
    const bh* __restrict__ hbf, const bh* __restrict__ w2t,
    const float* __restrict__ b2, const int* __restrict__ tok_buck,
    const float* __restrict__ gate_buck, const unsigned* __restrict__ cnt,
    const unsigned* __restrict__ offs, float* __restrict__ yv) {
  const int lid = blockIdx.x;
  const int xcd = lid & 7, idx = lid >> 3;
  const int nt = idx & 7, g = xcd * 16 + (idx >> 3);
  const int e = g >> 3, mt = g & 7;
  const int ne = (int)cnt[e];
  if (mt * 128 >= ne) return;
  __shared__ __align__(16) bh As[4][128 * 32];
  __shared__ __align__(16) bh Bs[4][128 * 32];
  const int tid = threadIdx.x;
  const int lane = tid & 63, wv = tid >> 6, wm = wv >> 1, wn_ = wv & 1;
  const int rowbase = (int)offs[e] + mt * 128;

  const bh* a_src[2]; const bh* b_src[2];
  int dst_off[2];
#pragma unroll
  for (int r = 0; r < 2; ++r) {
    int task = r * 256 + tid;
    int row = task >> 2, s = task & 3;
    a_src[r] = hbf + (size_t)(rowbase + row) * 2048 + ((s ^ (row & 3)) << 3);
    b_src[r] = w2t + (((size_t)e * 8 + nt) * 64) * 4096 + (size_t)task * 8;
    dst_off[r] = (r * 256 + (wv << 6)) << 4;
  }
  const int ln15 = lane & 15, q = lane >> 4;
  const int qs = ((q ^ (ln15 & 3)) << 3);
  int a_off[4], b_off[4];
#pragma unroll
  for (int i = 0; i < 4; ++i) {
    a_off[i] = (wm * 64 + i * 16 + ln15) * 32 + qs;
    b_off[i] = (wn_ * 64 + i * 16 + ln15) * 32 + qs;
  }
  fx4 zero = {0.f, 0.f, 0.f, 0.f};
  fx4 acc[4][4];
#pragma unroll
  for (int i = 0; i < 4; ++i)
#pragma unroll
    for (int j = 0; j < 4; ++j) acc[i][j] = zero;

  auto stage = [&](int qb, int kt) {
    const int ko = kt * 32;
    const size_t bo = (size_t)kt * 4096;
#pragma unroll
    for (int r = 0; r < 2; ++r) {
      gload16(a_src[r] + ko, (char*)(&As[qb][0]) + dst_off[r]);
      gload16(b_src[r] + bo, (char*)(&Bs[qb][0]) + dst_off[r]);
    }
  };

  const int NT = 64;
  stage(0, 0); stage(1, 1); stage(2, 2);
  asm volatile("s_waitcnt vmcnt(8)" ::: "memory");
  __builtin_amdgcn_s_barrier();

  for (int t = 0; t < NT; ++t) {
    if (t + 3 < NT) stage((t + 3) & 3, t + 3);
    const bh* Ab = &As[t & 3][0];
    const bh* Bb = &Bs[t & 3][0];
    bh8 af[4], bfr[4];
#pragma unroll
    for (int i = 0; i < 4; ++i) af[i] = *(const bh8*)(Ab + a_off[i]);
#pragma unroll
    for (int i = 0; i < 4; ++i) bfr[i] = *(const bh8*)(Bb + b_off[i]);
#pragma unroll
    for (int i = 0; i < 4; ++i)
#pragma unroll
      for (int j = 0; j < 4; ++j)
        acc[i][j] = __builtin_amdgcn_mfma_f32_16x16x32_bf16(af[i], bfr[j], acc[i][j], 0, 0, 0);
    if (t + 3 < NT)      asm volatile("s_waitcnt vmcnt(8) lgkmcnt(0)" ::: "memory");
    else if (t + 2 < NT) asm volatile("s_waitcnt vmcnt(4) lgkmcnt(0)" ::: "memory");
    else if (t + 1 < NT) asm volatile("s_waitcnt vmcnt(0) lgkmcnt(0)" ::: "memory");
    if (t + 1 < NT) __builtin_amdgcn_s_barrier();
  }

  int nrows = ne - mt * 128; if (nrows > 128) nrows = 128;
  int on[4]; float b2v[4];
#pragma unroll
  for (int j = 0; j < 4; ++j) {
    on[j] = nt * 128 + wn_ * 64 + j * 16 + ln15;
    b2v[j] = b2[e * 1024 + on[j]];
  }
#pragma unroll
  for (int i = 0; i < 4; ++i)
#pragma unroll
    for (int rr = 0; rr < 4; ++rr) {
      int ml = wm * 64 + i * 16 + q * 4 + rr;
      if (ml < nrows) {
        int pos = mt * 128 + ml;
        int bt = tok_buck[e * 1024 + pos];
        float gg = gate_buck[e * 1024 + pos];
        float* yrow = yv + (size_t)bt * 1024;
#pragma unroll
        for (int j = 0; j < 4; ++j)
          atomicAdd(&yrow[on[j]], gg * expf(acc[i][j][rr] + b2v[j]));
      }
    }
}

// ---------------- final log ----------------
__global__ __launch_bounds__(256) void k_log(float* __restrict__ yv) {
  const int i = blockIdx.x * 256 + threadIdx.x;
  fx4* p = (fx4*)yv + i;
  fx4 v = *p;
#pragma unroll
  for (int c = 0; c < 4; ++c) {
    float w = v[c];
    if (w == 0.f) w = 2.2204460492503131e-16f;
    v[c] = logf(w);
  }
  *p = v;
}

extern "C" void kernel_launch(void* const* d_in, const int* in_sizes, int n_in,
                              void* d_out, int out_size, void* d_ws, size_t ws_size,
                              hipStream_t stream) {
  const float* x  = (const float*)d_in[0];
  const float* wg = (const float*)d_in[1];
  const float* wn = (const float*)d_in[2];
  const float* W1 = (const float*)d_in[3];
  const float* b1 = (const float*)d_in[4];
  const float* W2 = (const float*)d_in[5];
  const float* b2 = (const float*)d_in[6];
  const float* nz = (const float*)d_in[7];
  float* out = (float*)d_out;

  // workspace layout (bytes)
  char* ws = (char*)d_ws;
  unsigned* cnt      = (unsigned*)(ws + 0);          // 64 B
  unsigned* offs     = (unsigned*)(ws + 64);         // 64 B
  float*    imp_part = (float*)(ws + 256);           // 64 KB
  float*    load_part= (float*)(ws + 256 + 65536);   // 64 KB
  int*      tok_buck = (int*)(ws + 256 + 2 * 65536); // 64 KB
  float*    gate_buck= (float*)(ws + 256 + 3 * 65536); // 64 KB
  bh*       xbf      = (bh*)(ws + 262400);           // 2 MB
  bh*       hbf      = (bh*)(ws + 2359552);          // (4096+128)*2048*2 = 16.5 MiB
  bh*       w1t      = (bh*)(ws + 19661056);         // 64 MiB (tiled)
  bh*       w2t      = (bh*)(ws + 86769920);         // 64 MiB (tiled)
  const size_t needed = 153878784;
  if (ws_size < needed) {
    // sentinel: distinguishable failure mode (absmax ~48) if ws is too small
    hipMemsetAsync(d_out, 0x42, (size_t)out_size * 4, stream);
    return;
  }

  hipMemsetAsync(d_out, 0, (size_t)out_size * 4, stream);
  hipMemsetAsync(cnt, 0, 64, stream);

  // W1 [e][1024][2048]: K=1024 (KT=32), N=2048 (NT=16)
  k_tcvt2<<<dim3(32, 16, 16), 256, 0, stream>>>(W1, w1t, 1024, 2048, 32, 16);
  // W2 [e][2048][1024]: K=2048 (KT=64), N=1024 (NT=8)
  k_tcvt2<<<dim3(64, 8, 16), 256, 0, stream>>>(W2, w2t, 2048, 1024, 64, 8);
  k_gating<<<1024, 256, 0, stream>>>(x, wg, wn, nz, xbf, cnt, tok_buck, gate_buck,
                                     imp_part, load_part);
  k_finalize<<<1, 256, 0, stream>>>(cnt, offs, imp_part, load_part, out + (out_size - 1));
  k_gemm1<<<2048, 256, 0, stream>>>(xbf, w1t, b1, tok_buck, cnt, offs, hbf);
  k_gemm2<<<1024, 256, 0, stream>>>(hbf, w2t, b2, tok_buck, gate_buck, cnt, offs, out);
  k_log<<<1024, 256, 0, stream>>>(out);
}

// Round 5
// 497.978 us; speedup vs baseline: 1.0318x; 1.0318x over previous
//
#include <hip/hip_runtime.h>
#include <cstdint>
#include <cstddef>

// Sizes fixed by the problem.
#define BTOK 1024
#define DDIM 1024
#define EEXP 16
#define HDIM 2048
#define ODIM 1024

typedef __bf16 bh;
typedef bh bh8 __attribute__((ext_vector_type(8)));
typedef bh bh4 __attribute__((ext_vector_type(4)));
typedef float fx4 __attribute__((ext_vector_type(4)));

// ---------------- transpose+convert+tile: fp32 [e][K][N] -> staging-ready tiles ----------------
// Output tile (e, nt, kt) is 4096 bh = 8 KB, contiguous; byte task*16 holds
// W[e][k0 + ((task&3)^(row&3))*8 + u][n0 + row], row = task>>2, u = 0..7 —
// the exact LDS image the GEMMs' COMPUTE expects when staged linearly.
__global__ __launch_bounds__(256) void k_tcvt2(const float* __restrict__ in,
                                               bh* __restrict__ out, int K, int N,
                                               int KT, int NT) {
  const int kt = blockIdx.x, nt = blockIdx.y, e = blockIdx.z;
  const int k0 = kt * 32, n0 = nt * 128;
  const float* pin = in + (size_t)e * K * N + (size_t)k0 * N + n0;
  bh* pout = out + (((size_t)e * NT + nt) * KT + kt) * 4096;
  __shared__ float t[32][129];
  const int tid = threadIdx.x;
#pragma unroll
  for (int rep = 0; rep < 4; ++rep) {
    int idx = rep * 256 + tid;
    int kk = idx >> 5, c4 = (idx & 31) << 2;
    fx4 v = *(const fx4*)(pin + (size_t)kk * N + c4);
#pragma unroll
    for (int u = 0; u < 4; ++u) t[kk][c4 + u] = v[u];
  }
  __syncthreads();
#pragma unroll
  for (int rep = 0; rep < 2; ++rep) {
    int task = rep * 256 + tid;
    int row = task >> 2, s = task & 3, o = s ^ (row & 3);
    bh8 w;
#pragma unroll
    for (int u = 0; u < 8; ++u) w[u] = (bh)t[o * 8 + u][row];
    *(bh8*)(pout + (size_t)task * 8) = w;
  }
}

// ---------------- gating: one block per token ----------------
__global__ __launch_bounds__(256) void k_gating(
    const float* __restrict__ x, const float* __restrict__ wg,
    const float* __restrict__ wn, const float* __restrict__ nz,
    bh* __restrict__ xbf, unsigned* __restrict__ cnt,
    int* __restrict__ tok_buck, float* __restrict__ gate_buck,
    float* __restrict__ imp_part, float* __restrict__ load_part) {
  const int b = blockIdx.x, tid = threadIdx.x;
  __shared__ __align__(16) float xs[1024];
  __shared__ float part[32][9];
  __shared__ float vals[32];
  fx4 v = *(const fx4*)(x + (size_t)b * 1024 + tid * 4);
  *(fx4*)(xs + tid * 4) = v;
  bh4 xb;
#pragma unroll
  for (int u = 0; u < 4; ++u) xb[u] = (bh)v[u];
  *(bh4*)(xbf + (size_t)b * 1024 + tid * 4) = xb;
  __syncthreads();
  const int col = tid & 31, g = tid >> 5;
  const float* wp = ((col < 16) ? wg : wn) + (col & 15);
  float s = 0.f;
  for (int it = g * 128; it < g * 128 + 128; ++it) s += xs[it] * wp[it * 16];
  part[col][g] = s;
  __syncthreads();
  if (tid < 32) {
    float tsum = 0.f;
#pragma unroll
    for (int gg = 0; gg < 8; ++gg) tsum += part[tid][gg];
    vals[tid] = tsum;
  }
  __syncthreads();
  if (tid == 0) {
    float clean[16], sd[16], noisy[16];
#pragma unroll
    for (int e = 0; e < 16; ++e) {
      clean[e] = vals[e];
      float raw = vals[16 + e];
      float sp = fmaxf(raw, 0.f) + log1pf(expf(-fabsf(raw)));
      sd[e] = sp + 0.1f;
      noisy[e] = clean[e] + nz[b * 16 + e] * sd[e];
    }
    float tv[5]; int ti[5]; unsigned used = 0;
    for (int r = 0; r < 5; ++r) {
      float bst = -INFINITY; int bi = 0;
      for (int e = 0; e < 16; ++e)
        if (!((used >> e) & 1u) && noisy[e] > bst) { bst = noisy[e]; bi = e; }
      used |= 1u << bi; tv[r] = bst; ti[r] = bi;
    }
    float gts[4]; float se = 0.f;
#pragma unroll
    for (int k = 0; k < 4; ++k) { gts[k] = expf(tv[k] - tv[0]); se += gts[k]; }
#pragma unroll
    for (int k = 0; k < 4; ++k) gts[k] /= se;
    const float thr_in = tv[4], thr_out = tv[3];
    float imp[16];
#pragma unroll
    for (int e = 0; e < 16; ++e) imp[e] = 0.f;
    for (int k = 0; k < 4; ++k) imp[ti[k]] = gts[k];
    for (int e = 0; e < 16; ++e) imp_part[b * 16 + e] = imp[e];
    for (int e = 0; e < 16; ++e) {
      bool is_in = noisy[e] > thr_in;
      float z = (clean[e] - (is_in ? thr_in : thr_out)) / sd[e];
      load_part[b * 16 + e] = 0.5f * (1.f + erff(z * 0.70710678118654752f));
    }
    for (int k = 0; k < 4; ++k) {
      int ee = ti[k];
      unsigned p = atomicAdd(&cnt[ee], 1u);
      tok_buck[ee * 1024 + (int)p] = b;
      gate_buck[ee * 1024 + (int)p] = gts[k];
    }
  }
}

__device__ __forceinline__ float cv2_16(const float* v) {
  float m = 0.f;
  for (int i = 0; i < 16; ++i) m += v[i];
  m *= (1.f / 16.f);
  float var = 0.f;
  for (int i = 0; i < 16; ++i) { float d = v[i] - m; var += d * d; }
  var *= (1.f / 15.f);
  return var / (m * m + 1e-10f);
}

// ---------------- offsets + loss ----------------
__global__ __launch_bounds__(256) void k_finalize(
    const unsigned* __restrict__ cnt, unsigned* __restrict__ offs,
    const float* __restrict__ imp_part, const float* __restrict__ load_part,
    float* __restrict__ loss_out) {
  const int tid = threadIdx.x;
  __shared__ float red[256];
  __shared__ float impv[16], loadv[16];
  const int e = tid & 15, p = tid >> 4;
  float s = 0.f;
  for (int r = 0; r < 64; ++r) s += imp_part[((p * 64 + r) << 4) + e];
  red[tid] = s;
  __syncthreads();
  if (tid < 16) {
    float t = 0.f;
    for (int pp = 0; pp < 16; ++pp) t += red[pp * 16 + tid];
    impv[tid] = t;
  }
  __syncthreads();
  s = 0.f;
  for (int r = 0; r < 64; ++r) s += load_part[((p * 64 + r) << 4) + e];
  red[tid] = s;
  __syncthreads();
  if (tid < 16) {
    float t = 0.f;
    for (int pp = 0; pp < 16; ++pp) t += red[pp * 16 + tid];
    loadv[tid] = t;
  }
  __syncthreads();
  if (tid == 0) {
    unsigned o = 0;
    for (int ee = 0; ee < 16; ++ee) { offs[ee] = o; o += cnt[ee]; }
    loss_out[0] = (cv2_16(impv) + cv2_16(loadv)) * 1e-4f;
  }
}

// ======== GEMM staging/compute macros (reg-staged, double-buffered) ========
// Loads go global->VGPR (per-lane scoreboard => high MLP on L2-cold data),
// then ds_write_b128 at byte task*16 — the SAME linear LDS image the
// verified gload_lds path produced, so fragment math is unchanged.
// Compiler manages all waitcnts (no inline asm => no race surface).

#define LOADR(AV, BV, KT) do {                                      \
  _Pragma("unroll") for (int r_ = 0; r_ < 2; ++r_) {                \
    AV[r_] = *(const fx4*)(a_src[r_] + (KT) * 32);                  \
    BV[r_] = *(const fx4*)(b_src[r_] + (size_t)(KT) * 4096);        \
  }                                                                 \
} while (0)

#define WRITELDS(BUF, AV, BV) do {                                  \
  _Pragma("unroll") for (int r_ = 0; r_ < 2; ++r_) {                \
    *(fx4*)((char*)(&As[BUF][0]) + wtask[r_]) = AV[r_];             \
    *(fx4*)((char*)(&Bs[BUF][0]) + wtask[r_]) = BV[r_];             \
  }                                                                 \
} while (0)

#define COMPUTE(BUF) do {                                           \
  bh8 af_[4], bf_[4];                                               \
  _Pragma("unroll") for (int i_ = 0; i_ < 4; ++i_)                  \
    af_[i_] = *(const bh8*)(&As[BUF][a_off[i_]]);                   \
  _Pragma("unroll") for (int i_ = 0; i_ < 4; ++i_)                  \
    bf_[i_] = *(const bh8*)(&Bs[BUF][b_off[i_]]);                   \
  _Pragma("unroll") for (int i_ = 0; i_ < 4; ++i_)                  \
    _Pragma("unroll") for (int j_ = 0; j_ < 4; ++j_)                \
      acc[i_][j_] = __builtin_amdgcn_mfma_f32_16x16x32_bf16(af_[i_], bf_[j_], acc[i_][j_], 0, 0, 0); \
} while (0)

// Per 2 K-steps: sync; write buf0; sync; compute buf0 (loads t+2 in flight);
// sync; write buf1; sync; compute buf1. Loads always issue one step ahead.
#define GEMM_MAIN(NT) do {                                          \
  LOADR(a0, b0, 0);                                                 \
  for (int t = 0; t < (NT); t += 2) {                               \
    __syncthreads();                                                \
    LOADR(a1, b1, t + 1);                                           \
    WRITELDS(0, a0, b0);                                            \
    __syncthreads();                                                \
    COMPUTE(0);                                                     \
    __syncthreads();                                                \
    if (t + 2 < (NT)) LOADR(a0, b0, t + 2);                         \
    WRITELDS(1, a1, b1);                                            \
    __syncthreads();                                                \
    COMPUTE(1);                                                     \
  }                                                                 \
} while (0)

// ---------------- GEMM1: h = relu(x @ W1[e] + b1[e]) for routed rows ----------------
// 1D grid, XCD-aware decode: all blocks of experts {2x,2x+1} on XCD x; B panel
// producers (k_tcvt2) and hbf consumers (k_gemm2) share the same expert->XCD map.
__global__ __launch_bounds__(256) void k_gemm1(
    const bh* __restrict__ xbf, const bh* __restrict__ w1t,
    const float* __restrict__ b1, const int* __restrict__ tok_buck,
    const unsigned* __restrict__ cnt, const unsigned* __restrict__ offs,
    bh* __restrict__ hbf) {
  const int lid = blockIdx.x;
  const int xcd = lid & 7, idx = lid >> 3;
  const int mt = idx & 7, g = xcd * 32 + (idx >> 3);
  const int e = g >> 4, nt = g & 15;
  const int ne = (int)cnt[e];
  if (mt * 128 >= ne) return;
  __shared__ __align__(16) bh As[2][128 * 32];
  __shared__ __align__(16) bh Bs[2][128 * 32];
  const int tid = threadIdx.x;
  const int lane = tid & 63, wv = tid >> 6, wm = wv >> 1, wn_ = wv & 1;

  const bh* a_src[2]; const bh* b_src[2];
  int wtask[2];
#pragma unroll
  for (int r = 0; r < 2; ++r) {
    int task = r * 256 + tid;
    int row = task >> 2, s = task & 3;
    int gm = mt * 128 + row; if (gm >= ne) gm = ne - 1;
    int tok = tok_buck[e * 1024 + gm];
    a_src[r] = xbf + (size_t)tok * 1024 + ((s ^ (row & 3)) << 3);
    b_src[r] = w1t + (((size_t)e * 16 + nt) * 32) * 4096 + (size_t)task * 8;
    wtask[r] = task * 16;  // byte offset of this thread's 16B in the buffer
  }
  const int ln15 = lane & 15, q = lane >> 4;
  const int qs = ((q ^ (ln15 & 3)) << 3);
  int a_off[4], b_off[4];
#pragma unroll
  for (int i = 0; i < 4; ++i) {
    a_off[i] = (wm * 64 + i * 16 + ln15) * 32 + qs;
    b_off[i] = (wn_ * 64 + i * 16 + ln15) * 32 + qs;
  }
  fx4 zero = {0.f, 0.f, 0.f, 0.f};
  fx4 acc[4][4];
#pragma unroll
  for (int i = 0; i < 4; ++i)
#pragma unroll
    for (int j = 0; j < 4; ++j) acc[i][j] = zero;

  fx4 a0[2], b0[2], a1[2], b1v_[2];
#define b1 b1  /* keep bias name */
  GEMM_MAIN_1: ;
  {
    // NT = 32
    LOADR(a0, b0, 0);
    for (int t = 0; t < 32; t += 2) {
      __syncthreads();
      LOADR(a1, b1v_, t + 1);
      WRITELDS(0, a0, b0);
      __syncthreads();
      COMPUTE(0);
      __syncthreads();
      if (t + 2 < 32) LOADR(a0, b0, t + 2);
      WRITELDS(1, a1, b1v_);
      __syncthreads();
      COMPUTE(1);
    }
  }

  int nrows = ne - mt * 128; if (nrows > 128) nrows = 128;
  int jn[4]; float b1b[4];
#pragma unroll
  for (int j = 0; j < 4; ++j) {
    jn[j] = nt * 128 + wn_ * 64 + j * 16 + ln15;
    b1b[j] = b1[e * 2048 + jn[j]];
  }
  const int rowbase = (int)offs[e] + mt * 128;
#pragma unroll
  for (int i = 0; i < 4; ++i)
#pragma unroll
    for (int rr = 0; rr < 4; ++rr) {
      int ml = wm * 64 + i * 16 + q * 4 + rr;
      if (ml < nrows) {
        size_t ro = (size_t)(rowbase + ml) * 2048;
#pragma unroll
        for (int j = 0; j < 4; ++j) {
          float vv = acc[i][j][rr] + b1b[j];
          hbf[ro + jn[j]] = (bh)fmaxf(vv, 0.f);
        }
      }
    }
}

// ---------------- GEMM2: y += gate * exp(h @ W2[e] + b2[e]) ----------------
__global__ __launch_bounds__(256) void k_gemm2(
    const bh* __restrict__ hbf, const bh* __restrict__ w2t,
    const float* __restrict__ b2, const int* __restrict__ tok_buck,
    const float* __restrict__ gate_buck, const unsigned* __restrict__ cnt,
    const unsigned* __restrict__ offs, float* __restrict__ yv) {
  const int lid = blockIdx.x;
  const int xcd = lid & 7, idx = lid >> 3;
  const int nt = idx & 7, g = xcd * 16 + (idx >> 3);
  const int e = g >> 3, mt = g & 7;
  const int ne = (int)cnt[e];
  if (mt * 128 >= ne) return;
  __shared__ __align__(16) bh As[2][128 * 32];
  __shared__ __align__(16) bh Bs[2][128 * 32];
  const int tid = threadIdx.x;
  const int lane = tid & 63, wv = tid >> 6, wm = wv >> 1, wn_ = wv & 1;
  const int rowbase = (int)offs[e] + mt * 128;

  const bh* a_src[2]; const bh* b_src[2];
  int wtask[2];
#pragma unroll
  for (int r = 0; r < 2; ++r) {
    int task = r * 256 + tid;
    int row = task >> 2, s = task & 3;
    a_src[r] = hbf + (size_t)(rowbase + row) * 2048 + ((s ^ (row & 3)) << 3);
    b_src[r] = w2t + (((size_t)e * 8 + nt) * 64) * 4096 + (size_t)task * 8;
    wtask[r] = task * 16;
  }
  const int ln15 = lane & 15, q = lane >> 4;
  const int qs = ((q ^ (ln15 & 3)) << 3);
  int a_off[4], b_off[4];
#pragma unroll
  for (int i = 0; i < 4; ++i) {
    a_off[i] = (wm * 64 + i * 16 + ln15) * 32 + qs;
    b_off[i] = (wn_ * 64 + i * 16 + ln15) * 32 + qs;
  }
  fx4 zero = {0.f, 0.f, 0.f, 0.f};
  fx4 acc[4][4];
#pragma unroll
  for (int i = 0; i < 4; ++i)
#pragma unroll
    for (int j = 0; j < 4; ++j) acc[i][j] = zero;

  fx4 a0[2], b0[2], a1[2], b1v_[2];
  {
    // NT = 64
    LOADR(a0, b0, 0);
    for (int t = 0; t < 64; t += 2) {
      __syncthreads();
      LOADR(a1, b1v_, t + 1);
      WRITELDS(0, a0, b0);
      __syncthreads();
      COMPUTE(0);
      __syncthreads();
      if (t + 2 < 64) LOADR(a0, b0, t + 2);
      WRITELDS(1, a1, b1v_);
      __syncthreads();
      COMPUTE(1);
    }
  }

  int nrows = ne - mt * 128; if (nrows > 128) nrows = 128;
  int on[4]; float b2v[4];
#pragma unroll
  for (int j = 0; j < 4; ++j) {
    on[j] = nt * 128 + wn_ * 64 + j * 16 + ln15;
    b2v[j] = b2[e * 1024 + on[j]];
  }
#pragma unroll
  for (int i = 0; i < 4; ++i)
#pragma unroll
    for (int rr = 0; rr < 4; ++rr) {
      int ml = wm * 64 + i * 16 + q * 4 + rr;
      if (ml < nrows) {
        int pos = mt * 128 + ml;
        int bt = tok_buck[e * 1024 + pos];
        float gg = gate_buck[e * 1024 + pos];
        float* yrow = yv + (size_t)bt * 1024;
#pragma unroll
        for (int j = 0; j < 4; ++j)
          atomicAdd(&yrow[on[j]], gg * expf(acc[i][j][rr] + b2v[j]));
      }
    }
}

// ---------------- final log ----------------
__global__ __launch_bounds__(256) void k_log(float* __restrict__ yv) {
  const int i = blockIdx.x * 256 + threadIdx.x;
  fx4* p = (fx4*)yv + i;
  fx4 v = *p;
#pragma unroll
  for (int c = 0; c < 4; ++c) {
    float w = v[c];
    if (w == 0.f) w = 2.2204460492503131e-16f;
    v[c] = logf(w);
  }
  *p = v;
}

extern "C" void kernel_launch(void* const* d_in, const int* in_sizes, int n_in,
                              void* d_out, int out_size, void* d_ws, size_t ws_size,
                              hipStream_t stream) {
  const float* x  = (const float*)d_in[0];
  const float* wg = (const float*)d_in[1];
  const float* wn = (const float*)d_in[2];
  const float* W1 = (const float*)d_in[3];
  const float* b1 = (const float*)d_in[4];
  const float* W2 = (const float*)d_in[5];
  const float* b2 = (const float*)d_in[6];
  const float* nz = (const float*)d_in[7];
  float* out = (float*)d_out;

  // workspace layout (bytes)
  char* ws = (char*)d_ws;
  unsigned* cnt      = (unsigned*)(ws + 0);          // 64 B
  unsigned* offs     = (unsigned*)(ws + 64);         // 64 B
  float*    imp_part = (float*)(ws + 256);           // 64 KB
  float*    load_part= (float*)(ws + 256 + 65536);   // 64 KB
  int*      tok_buck = (int*)(ws + 256 + 2 * 65536); // 64 KB
  float*    gate_buck= (float*)(ws + 256 + 3 * 65536); // 64 KB
  bh*       xbf      = (bh*)(ws + 262400);           // 2 MB
  bh*       hbf      = (bh*)(ws + 2359552);          // (4096+128)*2048*2 = 16.5 MiB
  bh*       w1t      = (bh*)(ws + 19661056);         // 64 MiB (tiled)
  bh*       w2t      = (bh*)(ws + 86769920);         // 64 MiB (tiled)
  const size_t needed = 153878784;
  if (ws_size < needed) {
    // sentinel: distinguishable failure mode (absmax ~48) if ws is too small
    hipMemsetAsync(d_out, 0x42, (size_t)out_size * 4, stream);
    return;
  }

  hipMemsetAsync(d_out, 0, (size_t)out_size * 4, stream);
  hipMemsetAsync(cnt, 0, 64, stream);

  // W1 [e][1024][2048]: K=1024 (KT=32), N=2048 (NT=16)
  k_tcvt2<<<dim3(32, 16, 16), 256, 0, stream>>>(W1, w1t, 1024, 2048, 32, 16);
  // W2 [e][2048][1024]: K=2048 (KT=64), N=1024 (NT=8)
  k_tcvt2<<<dim3(64, 8, 16), 256, 0, stream>>>(W2, w2t, 2048, 1024, 64, 8);
  k_gating<<<1024, 256, 0, stream>>>(x, wg, wn, nz, xbf, cnt, tok_buck, gate_buck,
                                     imp_part, load_part);
  k_finalize<<<1, 256, 0, stream>>>(cnt, offs, imp_part, load_part, out + (out_size - 1));
  k_gemm1<<<2048, 256, 0, stream>>>(xbf, w1t, b1, tok_buck, cnt, offs, hbf);
  k_gemm2<<<1024, 256, 0, stream>>>(hbf, w2t, b2, tok_buck, gate_buck, cnt, offs, out);
  k_log<<<1024, 256, 0, stream>>>(out);
}